// Round 1
// baseline (1778.469 us; speedup 1.0000x reference)
//
#include <hip/hip_runtime.h>
#include <hip/hip_bf16.h>

// Shapes: B=128, C=16, H=9, T=2048, L=9, TAU=1.0
// Input order (d_in): 0:x 1:gumbel 2:Wc1 3:bc1 4:bn1_g 5:bn1_b 6:a_c1 7:Wc2 8:bc2
//   9:bn2_g 10:bn2_b 11:a_c2 12:WP1 13:aP 14:WP2 15:WU1 16:aU 17:WU2 18:Wg1 19:ag1 20:Wg2 21:ag2
// Output: (B,2,C,H,L) float32

#define CB 16
#define HH 9
#define TT0 2048

__device__ __forceinline__ float ftanh(float x) {
    float e = __expf(2.f * x);
    return 1.f - 2.f / (e + 1.f);
}

__device__ __forceinline__ float fprelu(float v, float a) {
    return v >= 0.f ? v : a * v;
}

// ---------------- Front: conv33+BN+PReLU  ->  conv3+BN+PReLU ----------------
// Output layout: (B, H, T, C) channel-contiguous.
__global__ __launch_bounds__(256) void front_kernel(
    const float* __restrict__ x,
    const float* __restrict__ Wc1, const float* __restrict__ bc1,
    const float* __restrict__ bn1g, const float* __restrict__ bn1b,
    const float* __restrict__ ac1,
    const float* __restrict__ Wc2, const float* __restrict__ bc2,
    const float* __restrict__ bn2g, const float* __restrict__ bn2b,
    const float* __restrict__ ac2,
    float* __restrict__ y)
{
    const int tid  = threadIdx.x;
    const int tile = blockIdx.x;   // 0..8 (stride 254)
    const int h    = blockIdx.y;   // 0..8
    const int b    = blockIdx.z;   // 0..127
    const int t0   = tile * 254;

    __shared__ float lds_y[256 * 17];

    const float a1 = ac1[0], a2 = ac2[0];
    const int jy = t0 - 1 + tid;                 // stage-1 position this thread computes
    const float* xrow = x + (size_t)(b * HH + h) * TT0;

    float acc[CB];
#pragma unroll
    for (int cc = 0; cc < CB; ++cc) acc[cc] = bc1[cc];
    const bool yv = (jy >= 0 && jy < TT0);
    if (yv) {
        for (int k = 0; k < 33; ++k) {
            int u = jy + k - 16;
            float xvv = (u >= 0 && u < TT0) ? xrow[u] : 0.f;
#pragma unroll
            for (int cc = 0; cc < CB; ++cc)
                acc[cc] = fmaf(Wc1[cc * 33 + k], xvv, acc[cc]);
        }
    }
#pragma unroll
    for (int cc = 0; cc < CB; ++cc) {
        float v = fprelu(acc[cc] * bn1g[cc] + bn1b[cc], a1);
        lds_y[tid * 17 + cc] = yv ? v : 0.f;
    }
    __syncthreads();

    const int jt = t0 + tid;                     // stage-2 output position
    if (tid < 254 && jt < TT0) {
        float acc2[CB];
#pragma unroll
        for (int cc = 0; cc < CB; ++cc) acc2[cc] = bc2[cc];
#pragma unroll
        for (int k = 0; k < 3; ++k) {
            int u = jt + k - 1;
            if (u >= 0 && u < TT0) {
#pragma unroll
                for (int c2 = 0; c2 < CB; ++c2) {
                    float yvv = lds_y[(tid + k) * 17 + c2];
#pragma unroll
                    for (int cc = 0; cc < CB; ++cc)
                        acc2[cc] = fmaf(Wc2[(cc * CB + c2) * 3 + k], yvv, acc2[cc]);
                }
            }
        }
        float* orow = y + ((size_t)(b * HH + h) * TT0 + jt) * CB;
#pragma unroll
        for (int cc = 0; cc < CB; ++cc)
            orow[cc] = fprelu(acc2[cc] * bn2g[cc] + bn2b[cc], a2);
    }
}

// ---------------- One lifting level ----------------
// xin: (B,H,2t,C) — values must be multiplied by sm = m0prev[b] (1 for level 0).
// Computes c (-> xout, (B,H,t,C)) and row-sums of c and d -> rs[(2b+s)*16+cc)*9+h].
__global__ __launch_bounds__(256) void level_kernel(
    const float* __restrict__ xin, float* __restrict__ xout,
    float* __restrict__ rs, const float* __restrict__ m0prev,
    const float* __restrict__ WU1, const float* __restrict__ aUp,
    const float* __restrict__ WU2,
    const float* __restrict__ WP1, const float* __restrict__ aPp,
    const float* __restrict__ WP2,
    const int t)
{
    const int tid = threadIdx.x;
    const int row = blockIdx.x;          // b*9 + h
    const int b = row / 9, h = row % 9;
    const float sm = m0prev ? m0prev[b] : 1.0f;
    const float aU = aUp[0], aP = aPp[0];
    const float* xrow = xin + (size_t)row * (2 * t) * CB;
    float* orow = xout + (size_t)row * t * CB;

    __shared__ float lds_c[256 * 17];
    __shared__ float red[4][32];

    float sc[CB], sd[CB];
#pragma unroll
    for (int i = 0; i < CB; ++i) { sc[i] = 0.f; sd[i] = 0.f; }

    const int nt = (t + 253) / 254;
    for (int tile = 0; tile < nt; ++tile) {
        const int j0 = tile * 254;
        const int jc = j0 - 1 + tid;             // c position this thread computes
        const bool cvalid = (jc >= 0 && jc < t);

        if (cvalid) {
            // ---- U-branch: z = conv3(reflect(odd)); p = prelu; bu = tanh(conv1x1(p))
            float accz[CB];
#pragma unroll
            for (int i = 0; i < CB; ++i) accz[i] = 0.f;
#pragma unroll
            for (int k = 0; k < 3; ++k) {
                int u = jc - 1 + k;
                int um = u < 0 ? -u : (u >= t ? 2 * t - 2 - u : u);
                const float* op = xrow + (2 * um + 1) * CB;
                float ow[CB];
#pragma unroll
                for (int c2 = 0; c2 < CB; ++c2) ow[c2] = op[c2] * sm;
#pragma unroll
                for (int c2 = 0; c2 < CB; ++c2) {
#pragma unroll
                    for (int cc = 0; cc < CB; ++cc)
                        accz[cc] = fmaf(WU1[(cc * CB + c2) * 3 + k], ow[c2], accz[cc]);
                }
            }
#pragma unroll
            for (int i = 0; i < CB; ++i) accz[i] = fprelu(accz[i], aU);
            float bacc[CB];
#pragma unroll
            for (int cc = 0; cc < CB; ++cc) bacc[cc] = 0.f;
#pragma unroll
            for (int c2 = 0; c2 < CB; ++c2)
#pragma unroll
                for (int cc = 0; cc < CB; ++cc)
                    bacc[cc] = fmaf(WU2[cc * CB + c2], accz[c2], bacc[cc]);

            const float* ep = xrow + (2 * jc) * CB;
            float cv[CB];
#pragma unroll
            for (int cc = 0; cc < CB; ++cc)
                cv[cc] = ep[cc] * sm + ftanh(bacc[cc]);
#pragma unroll
            for (int cc = 0; cc < CB; ++cc) lds_c[tid * 17 + cc] = cv[cc];

            if (tid >= 1 && tid <= 254) {        // owned position: write + accumulate
                float* cop = orow + (size_t)jc * CB;
#pragma unroll
                for (int cc = 0; cc < CB; ++cc) { cop[cc] = cv[cc]; sc[cc] += cv[cc]; }
            }
        }
        __syncthreads();

        // ---- P-branch: d = odd - tanh(conv1x1(prelu(conv3(reflect(c)))))
        const int jd = j0 + tid;
        if (tid < 254 && jd < t) {
            float accz[CB];
#pragma unroll
            for (int i = 0; i < CB; ++i) accz[i] = 0.f;
#pragma unroll
            for (int k = 0; k < 3; ++k) {
                int u = jd - 1 + k;
                int um = u < 0 ? -u : (u >= t ? 2 * t - 2 - u : u);
                int li = um - (j0 - 1);
#pragma unroll
                for (int c2 = 0; c2 < CB; ++c2) {
                    float cvn = lds_c[li * 17 + c2];
#pragma unroll
                    for (int cc = 0; cc < CB; ++cc)
                        accz[cc] = fmaf(WP1[(cc * CB + c2) * 3 + k], cvn, accz[cc]);
                }
            }
#pragma unroll
            for (int i = 0; i < CB; ++i) accz[i] = fprelu(accz[i], aP);
            float bacc[CB];
#pragma unroll
            for (int cc = 0; cc < CB; ++cc) bacc[cc] = 0.f;
#pragma unroll
            for (int c2 = 0; c2 < CB; ++c2)
#pragma unroll
                for (int cc = 0; cc < CB; ++cc)
                    bacc[cc] = fmaf(WP2[cc * CB + c2], accz[c2], bacc[cc]);

            const float* op = xrow + (2 * jd + 1) * CB;
#pragma unroll
            for (int cc = 0; cc < CB; ++cc)
                sd[cc] += op[cc] * sm - ftanh(bacc[cc]);
        }
        __syncthreads();
    }

    // ---- cross-thread reduction of row sums (32 values) ----
    const int lane = tid & 63, wv = tid >> 6;
#pragma unroll
    for (int v = 0; v < 32; ++v) {
        float s = (v < CB) ? sc[v] : sd[v - CB];
#pragma unroll
        for (int off = 32; off >= 1; off >>= 1) s += __shfl_xor(s, off, 64);
        if (lane == 0) red[wv][v] = s;
    }
    __syncthreads();
    if (tid < 32) {
        float s = red[0][tid] + red[1][tid] + red[2][tid] + red[3][tid];
        int cc = tid & 15, sdx = tid >> 4;       // sdx: 0 = c, 1 = d
        rs[((2 * b + sdx) * CB + cc) * HH + h] = s;
    }
}

// ---------------- Gate: pooled -> PReLU(1x1) x2 -> softmax -> gumbel softmax ----
// Writes feats for level `li` into d_out and m0 (=m[b][0][0]) for the next level.
__global__ __launch_bounds__(256) void gate_kernel(
    const float* __restrict__ rs, const float* __restrict__ gn,
    const float* __restrict__ Wg1, const float* __restrict__ ag1p,
    const float* __restrict__ Wg2, const float* __restrict__ ag2p,
    float* __restrict__ out, float* __restrict__ m0buf,
    const int t, const int li)
{
    const int bj = threadIdx.x;                  // 0..255 = b*2 + s
    const float ag1 = ag1p[0], ag2 = ag2p[0];
    const float inv = 1.f / (9.f * (float)t);

    float pooled[CB];
#pragma unroll
    for (int cc = 0; cc < CB; ++cc) {
        float s = 0.f;
#pragma unroll
        for (int h = 0; h < HH; ++h) s += rs[(bj * CB + cc) * HH + h];
        pooled[cc] = s * inv;
    }
    float hm1[CB];
#pragma unroll
    for (int cc = 0; cc < CB; ++cc) {
        float s = 0.f;
#pragma unroll
        for (int c2 = 0; c2 < CB; ++c2) s = fmaf(Wg1[cc * CB + c2], pooled[c2], s);
        hm1[cc] = fprelu(s, ag1);
    }
    float h0 = 0.f, h1 = 0.f;
#pragma unroll
    for (int c2 = 0; c2 < CB; ++c2) {
        h0 = fmaf(Wg2[c2], hm1[c2], h0);
        h1 = fmaf(Wg2[CB + c2], hm1[c2], h1);
    }
    h0 = fprelu(h0, ag2); h1 = fprelu(h1, ag2);
    float mx = fmaxf(h0, h1);
    float e0 = __expf(h0 - mx), e1 = __expf(h1 - mx);
    float den = e0 + e1;
    float s0 = e0 / den, s1 = e1 / den;
    float a0 = s0 + gn[bj * 2 + 0], a1 = s1 + gn[bj * 2 + 1];   // TAU = 1
    float mx2 = fmaxf(a0, a1);
    float f0 = __expf(a0 - mx2), f1 = __expf(a1 - mx2);
    float den2 = f0 + f1;
    float m0 = f0 / den2, m1 = f1 / den2;

    const float scale = m1 / (float)t;           // feats = (rowsum/t) * m1
#pragma unroll
    for (int cc = 0; cc < CB; ++cc)
#pragma unroll
        for (int h = 0; h < HH; ++h)
            out[(size_t)((bj * CB + cc) * HH + h) * 9 + li] =
                rs[(bj * CB + cc) * HH + h] * scale;

    if ((bj & 1) == 0) m0buf[bj >> 1] = m0;      // next-level input scale
}

extern "C" void kernel_launch(void* const* d_in, const int* in_sizes, int n_in,
                              void* d_out, int out_size, void* d_ws, size_t ws_size,
                              hipStream_t stream) {
    const float* x    = (const float*)d_in[0];
    const float* gn   = (const float*)d_in[1];
    const float* Wc1  = (const float*)d_in[2];
    const float* bc1  = (const float*)d_in[3];
    const float* bn1g = (const float*)d_in[4];
    const float* bn1b = (const float*)d_in[5];
    const float* ac1  = (const float*)d_in[6];
    const float* Wc2  = (const float*)d_in[7];
    const float* bc2  = (const float*)d_in[8];
    const float* bn2g = (const float*)d_in[9];
    const float* bn2b = (const float*)d_in[10];
    const float* ac2  = (const float*)d_in[11];
    const float* WP1  = (const float*)d_in[12];
    const float* aP   = (const float*)d_in[13];
    const float* WP2  = (const float*)d_in[14];
    const float* WU1  = (const float*)d_in[15];
    const float* aU   = (const float*)d_in[16];
    const float* WU2  = (const float*)d_in[17];
    const float* Wg1  = (const float*)d_in[18];
    const float* ag1  = (const float*)d_in[19];
    const float* Wg2  = (const float*)d_in[20];
    const float* ag2  = (const float*)d_in[21];
    float* out = (float*)d_out;

    char* ws = (char*)d_ws;
    const size_t szA = (size_t)128 * 9 * 2048 * 16 * 4;   // 150,994,944
    const size_t szB = szA / 2;                            //  75,497,472
    float* bufA = (float*)ws;
    float* bufB = (float*)(ws + szA);
    float* rs   = (float*)(ws + szA + szB);
    float* m0b  = (float*)(ws + szA + szB + 256 * 16 * 9 * 4);

    dim3 fgrid(9, 9, 128);   // tiles(254) x H x B
    front_kernel<<<fgrid, 256, 0, stream>>>(x, Wc1, bc1, bn1g, bn1b, ac1,
                                            Wc2, bc2, bn2g, bn2b, ac2, bufA);

    float* cur = bufA;
    float* nxt = bufB;
    int t = 1024;
    for (int i = 0; i < 9; ++i) {
        level_kernel<<<128 * 9, 256, 0, stream>>>(
            cur, nxt, rs, (i == 0) ? nullptr : m0b,
            WU1 + i * 768, aU + i, WU2 + i * 256,
            WP1 + i * 768, aP + i, WP2 + i * 256, t);
        gate_kernel<<<1, 256, 0, stream>>>(
            rs, gn + i * 512, Wg1 + i * 256, ag1 + i, Wg2 + i * 32, ag2 + i,
            out, m0b, t, i);
        float* tmp = cur; cur = nxt; nxt = tmp;
        t >>= 1;
    }
}

// Round 2
// 1617.574 us; speedup vs baseline: 1.0995x; 1.0995x over previous
//
#include <hip/hip_runtime.h>
#include <hip/hip_bf16.h>

// Shapes: B=128, C=16, H=9, T=2048, L=9, TAU=1.0
// Output: (B,2,C,H,L) float32

#define CB 16
#define HH 9
#define TT0 2048
#define RS_SLOT 36864   // 256*16*9 floats per tile slot

__device__ __forceinline__ float ftanh(float x) {
    float e = __expf(2.f * x);
    return 1.f - 2.f / (e + 1.f);
}
__device__ __forceinline__ float fprelu(float v, float a) {
    return v >= 0.f ? v : a * v;
}
__device__ __forceinline__ void ld16(const float* p, float* v) {
#pragma unroll
    for (int q = 0; q < 4; ++q) {
        float4 f = *(const float4*)(p + 4 * q);
        v[4 * q] = f.x; v[4 * q + 1] = f.y; v[4 * q + 2] = f.z; v[4 * q + 3] = f.w;
    }
}
__device__ __forceinline__ void st16(float* p, const float* v) {
#pragma unroll
    for (int q = 0; q < 4; ++q) {
        float4 f; f.x = v[4 * q]; f.y = v[4 * q + 1]; f.z = v[4 * q + 2]; f.w = v[4 * q + 3];
        *(float4*)(p + 4 * q) = f;
    }
}

// Block-level reduction of 16 per-thread values -> rs slot (sdx: 0=c stream, 1=d stream)
__device__ __forceinline__ void rowsum_reduce(float* vals, float* rs, int tile,
                                              int b, int h, int sdx, int tid) {
    __shared__ float red[4 * CB];
    const int lane = tid & 63, wv = tid >> 6;
#pragma unroll
    for (int cc = 0; cc < CB; ++cc) {
        float s = vals[cc];
#pragma unroll
        for (int off = 32; off >= 1; off >>= 1) s += __shfl_xor(s, off, 64);
        if (lane == cc) red[wv * CB + cc] = s;
    }
    __syncthreads();
    if (tid < CB) {
        float s = red[tid] + red[CB + tid] + red[2 * CB + tid] + red[3 * CB + tid];
        rs[(size_t)tile * RS_SLOT + ((size_t)(2 * b + sdx) * CB + tid) * HH + h] = s;
    }
}

// ---------------- Front: conv33+BN+PReLU -> conv3(16x16)+BN+PReLU ----------------
// Output layout (B,H,T,C) channel-contiguous.
__global__ __launch_bounds__(256, 4) void front_kernel(
    const float* __restrict__ x,
    const float* __restrict__ Wc1, const float* __restrict__ bc1,
    const float* __restrict__ bn1g, const float* __restrict__ bn1b,
    const float* __restrict__ ac1,
    const float* __restrict__ Wc2, const float* __restrict__ bc2,
    const float* __restrict__ bn2g, const float* __restrict__ bn2b,
    const float* __restrict__ ac2,
    float* __restrict__ y)
{
    const int tid = threadIdx.x;
    const int t0  = blockIdx.x * 254;   // 9 tiles
    const int h   = blockIdx.y;
    const int b   = blockIdx.z;

    __shared__ float lds_x[288];
    __shared__ float lds_y[256 * 20];   // pitch 20 floats (80B, 16B-aligned)

    const float* xrow = x + (size_t)(b * HH + h) * TT0;
    {
        int g = t0 - 17 + tid;
        lds_x[tid] = (g >= 0 && g < TT0) ? xrow[g] : 0.f;
        if (tid < 32) {
            int g2 = t0 + 239 + tid;
            lds_x[256 + tid] = (g2 >= 0 && g2 < TT0) ? xrow[g2] : 0.f;
        }
    }
    __syncthreads();

    const float a1 = ac1[0], a2 = ac2[0];
    float acc[CB];
#pragma unroll
    for (int cc = 0; cc < CB; ++cc) acc[cc] = bc1[cc];
#pragma unroll
    for (int k = 0; k < 33; ++k) {
        float xv = lds_x[tid + k];
#pragma unroll
        for (int cc = 0; cc < CB; ++cc) acc[cc] = fmaf(Wc1[cc * 33 + k], xv, acc[cc]);
    }
#pragma unroll
    for (int cc = 0; cc < CB; ++cc)
        lds_y[tid * 20 + cc] = fprelu(acc[cc] * bn1g[cc] + bn1b[cc], a1);
    __syncthreads();

    const int jt = t0 + tid;
    if (tid < 254 && jt < TT0) {
        float acc2[CB];
#pragma unroll
        for (int cc = 0; cc < CB; ++cc) acc2[cc] = bc2[cc];
#pragma unroll
        for (int k = 0; k < 3; ++k) {
            int u = jt - 1 + k;
            if (u >= 0 && u < TT0) {
                float yv[CB];
                ld16(&lds_y[(tid + k) * 20], yv);
#pragma unroll
                for (int c2 = 0; c2 < CB; ++c2) {
                    float yvv = yv[c2];
#pragma unroll
                    for (int cc = 0; cc < CB; ++cc)
                        acc2[cc] = fmaf(Wc2[(cc * CB + c2) * 3 + k], yvv, acc2[cc]);
                }
            }
        }
        float ov[CB];
#pragma unroll
        for (int cc = 0; cc < CB; ++cc) ov[cc] = fprelu(acc2[cc] * bn2g[cc] + bn2b[cc], a2);
        st16(y + ((size_t)(b * HH + h) * TT0 + jt) * CB, ov);
    }
}

// ---------------- c-phase: c[j] = sm*even[j] + tanh(sm*U(odd)) ----------------
__global__ __launch_bounds__(256, 4) void c_kernel(
    const float* __restrict__ xin, float* __restrict__ xout,
    float* __restrict__ rs, const float* __restrict__ m0prev,
    const float* __restrict__ WU1, const float* __restrict__ aUp,
    const float* __restrict__ WU2, const int t)
{
    const int tid = threadIdx.x;
    const int row = blockIdx.x;            // b*9+h
    const int tile = blockIdx.y;
    const int b = row / 9, h = row - 9 * b;
    const float sm = m0prev ? m0prev[b] : 1.f;
    const float aU = aUp[0];
    const float* xrow = xin + (size_t)row * (2 * t) * CB;
    const int j = tile * 256 + tid;

    float cv[CB];
#pragma unroll
    for (int i = 0; i < CB; ++i) cv[i] = 0.f;

    if (j < t) {
        float accz[CB];
#pragma unroll
        for (int i = 0; i < CB; ++i) accz[i] = 0.f;
#pragma unroll
        for (int k = 0; k < 3; ++k) {
            int u = j - 1 + k;
            int um = u < 0 ? -u : (u >= t ? 2 * t - 2 - u : u);
            float ow[CB];
            ld16(xrow + (2 * um + 1) * CB, ow);
#pragma unroll
            for (int c2 = 0; c2 < CB; ++c2) {
                float o = ow[c2];
#pragma unroll
                for (int cc = 0; cc < CB; ++cc)
                    accz[cc] = fmaf(WU1[(cc * CB + c2) * 3 + k], o, accz[cc]);
            }
        }
#pragma unroll
        for (int i = 0; i < CB; ++i) accz[i] = fprelu(accz[i], aU);
        float bacc[CB];
#pragma unroll
        for (int cc = 0; cc < CB; ++cc) bacc[cc] = 0.f;
#pragma unroll
        for (int c2 = 0; c2 < CB; ++c2) {
            float z = accz[c2];
#pragma unroll
            for (int cc = 0; cc < CB; ++cc)
                bacc[cc] = fmaf(WU2[cc * CB + c2], z, bacc[cc]);
        }
        float ev[CB];
        ld16(xrow + (size_t)(2 * j) * CB, ev);
#pragma unroll
        for (int cc = 0; cc < CB; ++cc)
            cv[cc] = sm * ev[cc] + ftanh(sm * bacc[cc]);
        st16(xout + ((size_t)row * t + j) * CB, cv);
    }
    rowsum_reduce(cv, rs, tile, b, h, 0, tid);
}

// ---------------- d-phase: d[j] = sm*odd[j] - tanh(P(c)); only row-sums kept ----
__global__ __launch_bounds__(256, 4) void d_kernel(
    const float* __restrict__ xin, const float* __restrict__ cbuf,
    float* __restrict__ rs, const float* __restrict__ m0prev,
    const float* __restrict__ WP1, const float* __restrict__ aPp,
    const float* __restrict__ WP2, const int t)
{
    const int tid = threadIdx.x;
    const int row = blockIdx.x;
    const int tile = blockIdx.y;
    const int b = row / 9, h = row - 9 * b;
    const float sm = m0prev ? m0prev[b] : 1.f;
    const float aP = aPp[0];
    const float* xrow = xin + (size_t)row * (2 * t) * CB;
    const float* crow = cbuf + (size_t)row * t * CB;
    const int j = tile * 256 + tid;

    float dv[CB];
#pragma unroll
    for (int i = 0; i < CB; ++i) dv[i] = 0.f;

    if (j < t) {
        float accz[CB];
#pragma unroll
        for (int i = 0; i < CB; ++i) accz[i] = 0.f;
#pragma unroll
        for (int k = 0; k < 3; ++k) {
            int u = j - 1 + k;
            int um = u < 0 ? -u : (u >= t ? 2 * t - 2 - u : u);
            float cw[CB];
            ld16(crow + (size_t)um * CB, cw);
#pragma unroll
            for (int c2 = 0; c2 < CB; ++c2) {
                float o = cw[c2];
#pragma unroll
                for (int cc = 0; cc < CB; ++cc)
                    accz[cc] = fmaf(WP1[(cc * CB + c2) * 3 + k], o, accz[cc]);
            }
        }
#pragma unroll
        for (int i = 0; i < CB; ++i) accz[i] = fprelu(accz[i], aP);
        float bacc[CB];
#pragma unroll
        for (int cc = 0; cc < CB; ++cc) bacc[cc] = 0.f;
#pragma unroll
        for (int c2 = 0; c2 < CB; ++c2) {
            float z = accz[c2];
#pragma unroll
            for (int cc = 0; cc < CB; ++cc)
                bacc[cc] = fmaf(WP2[cc * CB + c2], z, bacc[cc]);
        }
        float ov[CB];
        ld16(xrow + (size_t)(2 * j + 1) * CB, ov);
#pragma unroll
        for (int cc = 0; cc < CB; ++cc)
            dv[cc] = sm * ov[cc] - ftanh(bacc[cc]);
    }
    rowsum_reduce(dv, rs, tile, b, h, 1, tid);
}

// ---------------- Gate ----------------
__global__ __launch_bounds__(256) void gate_kernel(
    const float* __restrict__ rs, const float* __restrict__ gn,
    const float* __restrict__ Wg1, const float* __restrict__ ag1p,
    const float* __restrict__ Wg2, const float* __restrict__ ag2p,
    float* __restrict__ out, float* __restrict__ m0buf,
    const int t, const int nt, const int li)
{
    const int bj = threadIdx.x;                  // b*2 + s
    const float ag1 = ag1p[0], ag2 = ag2p[0];
    const float inv = 1.f / (9.f * (float)t);

    float pooled[CB];
#pragma unroll
    for (int cc = 0; cc < CB; ++cc) {
        float s = 0.f;
        for (int tl = 0; tl < nt; ++tl)
#pragma unroll
            for (int h = 0; h < HH; ++h)
                s += rs[(size_t)tl * RS_SLOT + ((size_t)bj * CB + cc) * HH + h];
        pooled[cc] = s * inv;
    }
    float hm1[CB];
#pragma unroll
    for (int cc = 0; cc < CB; ++cc) {
        float s = 0.f;
#pragma unroll
        for (int c2 = 0; c2 < CB; ++c2) s = fmaf(Wg1[cc * CB + c2], pooled[c2], s);
        hm1[cc] = fprelu(s, ag1);
    }
    float h0 = 0.f, h1 = 0.f;
#pragma unroll
    for (int c2 = 0; c2 < CB; ++c2) {
        h0 = fmaf(Wg2[c2], hm1[c2], h0);
        h1 = fmaf(Wg2[CB + c2], hm1[c2], h1);
    }
    h0 = fprelu(h0, ag2); h1 = fprelu(h1, ag2);
    float mx = fmaxf(h0, h1);
    float e0 = __expf(h0 - mx), e1 = __expf(h1 - mx);
    float s0 = e0 / (e0 + e1), s1 = e1 / (e0 + e1);
    float a0 = s0 + gn[bj * 2 + 0], a1 = s1 + gn[bj * 2 + 1];   // TAU = 1
    float mx2 = fmaxf(a0, a1);
    float f0 = __expf(a0 - mx2), f1 = __expf(a1 - mx2);
    float m0 = f0 / (f0 + f1), m1 = f1 / (f0 + f1);

    const float scale = m1 / (float)t;
#pragma unroll
    for (int cc = 0; cc < CB; ++cc)
#pragma unroll
        for (int h = 0; h < HH; ++h) {
            float s = 0.f;
            for (int tl = 0; tl < nt; ++tl)
                s += rs[(size_t)tl * RS_SLOT + ((size_t)bj * CB + cc) * HH + h];
            out[(size_t)((bj * CB + cc) * HH + h) * 9 + li] = s * scale;
        }

    if ((bj & 1) == 0) m0buf[bj >> 1] = m0;
}

extern "C" void kernel_launch(void* const* d_in, const int* in_sizes, int n_in,
                              void* d_out, int out_size, void* d_ws, size_t ws_size,
                              hipStream_t stream) {
    const float* x    = (const float*)d_in[0];
    const float* gn   = (const float*)d_in[1];
    const float* Wc1  = (const float*)d_in[2];
    const float* bc1  = (const float*)d_in[3];
    const float* bn1g = (const float*)d_in[4];
    const float* bn1b = (const float*)d_in[5];
    const float* ac1  = (const float*)d_in[6];
    const float* Wc2  = (const float*)d_in[7];
    const float* bc2  = (const float*)d_in[8];
    const float* bn2g = (const float*)d_in[9];
    const float* bn2b = (const float*)d_in[10];
    const float* ac2  = (const float*)d_in[11];
    const float* WP1  = (const float*)d_in[12];
    const float* aP   = (const float*)d_in[13];
    const float* WP2  = (const float*)d_in[14];
    const float* WU1  = (const float*)d_in[15];
    const float* aU   = (const float*)d_in[16];
    const float* WU2  = (const float*)d_in[17];
    const float* Wg1  = (const float*)d_in[18];
    const float* ag1  = (const float*)d_in[19];
    const float* Wg2  = (const float*)d_in[20];
    const float* ag2  = (const float*)d_in[21];
    float* out = (float*)d_out;

    char* ws = (char*)d_ws;
    const size_t sz0 = (size_t)128 * 9 * 2048 * 16 * 4;   // 150,994,944
    const size_t sz1 = sz0 / 2;                            //  75,497,472
    float* buf0 = (float*)ws;
    float* buf1 = (float*)(ws + sz0);
    float* rs   = (float*)(ws + sz0 + sz1);
    float* m0b  = (float*)(ws + sz0 + sz1 + (size_t)4 * RS_SLOT * 4);

    dim3 fgrid(9, 9, 128);
    front_kernel<<<fgrid, 256, 0, stream>>>(x, Wc1, bc1, bn1g, bn1b, ac1,
                                            Wc2, bc2, bn2g, bn2b, ac2, buf0);

    float* cur = buf0;
    float* nxt = buf1;
    int t = 1024;
    for (int i = 0; i < 9; ++i) {
        const int nt = (t + 255) >> 8;
        const float* m0p = (i == 0) ? nullptr : m0b;
        dim3 lgrid(128 * 9, nt);
        c_kernel<<<lgrid, 256, 0, stream>>>(cur, nxt, rs, m0p,
                                            WU1 + i * 768, aU + i, WU2 + i * 256, t);
        d_kernel<<<lgrid, 256, 0, stream>>>(cur, nxt, rs, m0p,
                                            WP1 + i * 768, aP + i, WP2 + i * 256, t);
        gate_kernel<<<1, 256, 0, stream>>>(
            rs, gn + i * 512, Wg1 + i * 256, ag1 + i, Wg2 + i * 32, ag2 + i,
            out, m0b, t, nt, i);
        float* tmp = cur; cur = nxt; nxt = tmp;
        t >>= 1;
    }
}

// Round 3
// 1186.351 us; speedup vs baseline: 1.4991x; 1.3635x over previous
//
#include <hip/hip_runtime.h>
#include <hip/hip_bf16.h>

// Shapes: B=128, C=16, H=9, T=2048, L=9, TAU=1.0
// Output: (B,2,C,H,L) float32

#define CB 16
#define HH 9
#define TT0 2048
#define RS_SLOT 36864   // 256*16*9 floats per tile slot

__device__ __forceinline__ float ftanh(float x) {
    float e = __expf(2.f * x);
    return 1.f - 2.f / (e + 1.f);
}
__device__ __forceinline__ float fprelu(float v, float a) {
    return v >= 0.f ? v : a * v;
}
__device__ __forceinline__ void ld16(const float* p, float* v) {
#pragma unroll
    for (int q = 0; q < 4; ++q) {
        float4 f = *(const float4*)(p + 4 * q);
        v[4 * q] = f.x; v[4 * q + 1] = f.y; v[4 * q + 2] = f.z; v[4 * q + 3] = f.w;
    }
}
__device__ __forceinline__ void st16(float* p, const float* v) {
#pragma unroll
    for (int q = 0; q < 4; ++q) {
        float4 f; f.x = v[4 * q]; f.y = v[4 * q + 1]; f.z = v[4 * q + 2]; f.w = v[4 * q + 3];
        *(float4*)(p + 4 * q) = f;
    }
}

// Block-level reduction of 16 per-thread values -> rs slot (sdx: 0=c stream, 1=d stream)
__device__ __forceinline__ void rowsum_reduce(float* vals, float* rs, int tile,
                                              int b, int h, int sdx, int tid) {
    __shared__ float red[4 * CB];
    const int lane = tid & 63, wv = tid >> 6;
#pragma unroll
    for (int cc = 0; cc < CB; ++cc) {
        float s = vals[cc];
#pragma unroll
        for (int off = 32; off >= 1; off >>= 1) s += __shfl_xor(s, off, 64);
        if (lane == cc) red[wv * CB + cc] = s;
    }
    __syncthreads();
    if (tid < CB) {
        float s = red[tid] + red[CB + tid] + red[2 * CB + tid] + red[3 * CB + tid];
        rs[(size_t)tile * RS_SLOT + ((size_t)(2 * b + sdx) * CB + tid) * HH + h] = s;
    }
}

// ---------------- Front: conv33+BN+PReLU -> conv3(16x16)+BN+PReLU ----------------
// Output layout (B,H,T,C) channel-contiguous.
__global__ __launch_bounds__(256, 4) void front_kernel(
    const float* __restrict__ x,
    const float* __restrict__ Wc1, const float* __restrict__ bc1,
    const float* __restrict__ bn1g, const float* __restrict__ bn1b,
    const float* __restrict__ ac1,
    const float* __restrict__ Wc2, const float* __restrict__ bc2,
    const float* __restrict__ bn2g, const float* __restrict__ bn2b,
    const float* __restrict__ ac2,
    float* __restrict__ y)
{
    const int tid = threadIdx.x;
    const int t0  = blockIdx.x * 254;   // 9 tiles
    const int h   = blockIdx.y;
    const int b   = blockIdx.z;

    __shared__ float lds_x[288];
    __shared__ float lds_y[256 * 20];   // pitch 20 floats (80B, 16B-aligned)

    const float* xrow = x + (size_t)(b * HH + h) * TT0;
    {
        int g = t0 - 17 + tid;
        lds_x[tid] = (g >= 0 && g < TT0) ? xrow[g] : 0.f;
        if (tid < 32) {
            int g2 = t0 + 239 + tid;
            lds_x[256 + tid] = (g2 >= 0 && g2 < TT0) ? xrow[g2] : 0.f;
        }
    }
    __syncthreads();

    const float a1 = ac1[0], a2 = ac2[0];
    float acc[CB];
#pragma unroll
    for (int cc = 0; cc < CB; ++cc) acc[cc] = bc1[cc];
#pragma unroll
    for (int k = 0; k < 33; ++k) {
        float xv = lds_x[tid + k];
#pragma unroll
        for (int cc = 0; cc < CB; ++cc) acc[cc] = fmaf(Wc1[cc * 33 + k], xv, acc[cc]);
    }
#pragma unroll
    for (int cc = 0; cc < CB; ++cc)
        lds_y[tid * 20 + cc] = fprelu(acc[cc] * bn1g[cc] + bn1b[cc], a1);
    __syncthreads();

    const int jt = t0 + tid;
    if (tid < 254 && jt < TT0) {
        float acc2[CB];
#pragma unroll
        for (int cc = 0; cc < CB; ++cc) acc2[cc] = bc2[cc];
#pragma unroll
        for (int k = 0; k < 3; ++k) {
            int u = jt - 1 + k;
            if (u >= 0 && u < TT0) {
                float yv[CB];
                ld16(&lds_y[(tid + k) * 20], yv);
#pragma unroll
                for (int c2 = 0; c2 < CB; ++c2) {
                    float yvv = yv[c2];
#pragma unroll
                    for (int cc = 0; cc < CB; ++cc)
                        acc2[cc] = fmaf(Wc2[(cc * CB + c2) * 3 + k], yvv, acc2[cc]);
                }
            }
        }
        float ov[CB];
#pragma unroll
        for (int cc = 0; cc < CB; ++cc) ov[cc] = fprelu(acc2[cc] * bn2g[cc] + bn2b[cc], a2);
        st16(y + ((size_t)(b * HH + h) * TT0 + jt) * CB, ov);
    }
}

// ---------------- c-phase: c[j] = sm*even[j] + tanh(sm*U(odd)) ----------------
__global__ __launch_bounds__(256, 4) void c_kernel(
    const float* __restrict__ xin, float* __restrict__ xout,
    float* __restrict__ rs, const float* __restrict__ m0prev,
    const float* __restrict__ WU1, const float* __restrict__ aUp,
    const float* __restrict__ WU2, const int t)
{
    const int tid = threadIdx.x;
    const int row = blockIdx.x;            // b*9+h
    const int tile = blockIdx.y;
    const int b = row / 9, h = row - 9 * b;
    const float sm = m0prev ? m0prev[b] : 1.f;
    const float aU = aUp[0];
    const float* xrow = xin + (size_t)row * (2 * t) * CB;
    const int j = tile * 256 + tid;

    float cv[CB];
#pragma unroll
    for (int i = 0; i < CB; ++i) cv[i] = 0.f;

    if (j < t) {
        float accz[CB];
#pragma unroll
        for (int i = 0; i < CB; ++i) accz[i] = 0.f;
#pragma unroll
        for (int k = 0; k < 3; ++k) {
            int u = j - 1 + k;
            int um = u < 0 ? -u : (u >= t ? 2 * t - 2 - u : u);
            float ow[CB];
            ld16(xrow + (2 * um + 1) * CB, ow);
#pragma unroll
            for (int c2 = 0; c2 < CB; ++c2) {
                float o = ow[c2];
#pragma unroll
                for (int cc = 0; cc < CB; ++cc)
                    accz[cc] = fmaf(WU1[(cc * CB + c2) * 3 + k], o, accz[cc]);
            }
        }
#pragma unroll
        for (int i = 0; i < CB; ++i) accz[i] = fprelu(accz[i], aU);
        float bacc[CB];
#pragma unroll
        for (int cc = 0; cc < CB; ++cc) bacc[cc] = 0.f;
#pragma unroll
        for (int c2 = 0; c2 < CB; ++c2) {
            float z = accz[c2];
#pragma unroll
            for (int cc = 0; cc < CB; ++cc)
                bacc[cc] = fmaf(WU2[cc * CB + c2], z, bacc[cc]);
        }
        float ev[CB];
        ld16(xrow + (size_t)(2 * j) * CB, ev);
#pragma unroll
        for (int cc = 0; cc < CB; ++cc)
            cv[cc] = sm * ev[cc] + ftanh(sm * bacc[cc]);
        st16(xout + ((size_t)row * t + j) * CB, cv);
    }
    rowsum_reduce(cv, rs, tile, b, h, 0, tid);
}

// ---------------- d-phase: d[j] = sm*odd[j] - tanh(P(c)); only row-sums kept ----
__global__ __launch_bounds__(256, 4) void d_kernel(
    const float* __restrict__ xin, const float* __restrict__ cbuf,
    float* __restrict__ rs, const float* __restrict__ m0prev,
    const float* __restrict__ WP1, const float* __restrict__ aPp,
    const float* __restrict__ WP2, const int t)
{
    const int tid = threadIdx.x;
    const int row = blockIdx.x;
    const int tile = blockIdx.y;
    const int b = row / 9, h = row - 9 * b;
    const float sm = m0prev ? m0prev[b] : 1.f;
    const float aP = aPp[0];
    const float* xrow = xin + (size_t)row * (2 * t) * CB;
    const float* crow = cbuf + (size_t)row * t * CB;
    const int j = tile * 256 + tid;

    float dv[CB];
#pragma unroll
    for (int i = 0; i < CB; ++i) dv[i] = 0.f;

    if (j < t) {
        float accz[CB];
#pragma unroll
        for (int i = 0; i < CB; ++i) accz[i] = 0.f;
#pragma unroll
        for (int k = 0; k < 3; ++k) {
            int u = j - 1 + k;
            int um = u < 0 ? -u : (u >= t ? 2 * t - 2 - u : u);
            float cw[CB];
            ld16(crow + (size_t)um * CB, cw);
#pragma unroll
            for (int c2 = 0; c2 < CB; ++c2) {
                float o = cw[c2];
#pragma unroll
                for (int cc = 0; cc < CB; ++cc)
                    accz[cc] = fmaf(WP1[(cc * CB + c2) * 3 + k], o, accz[cc]);
            }
        }
#pragma unroll
        for (int i = 0; i < CB; ++i) accz[i] = fprelu(accz[i], aP);
        float bacc[CB];
#pragma unroll
        for (int cc = 0; cc < CB; ++cc) bacc[cc] = 0.f;
#pragma unroll
        for (int c2 = 0; c2 < CB; ++c2) {
            float z = accz[c2];
#pragma unroll
            for (int cc = 0; cc < CB; ++cc)
                bacc[cc] = fmaf(WP2[cc * CB + c2], z, bacc[cc]);
        }
        float ov[CB];
        ld16(xrow + (size_t)(2 * j + 1) * CB, ov);
#pragma unroll
        for (int cc = 0; cc < CB; ++cc)
            dv[cc] = sm * ov[cc] - ftanh(bacc[cc]);
    }
    rowsum_reduce(dv, rs, tile, b, h, 1, tid);
}

// ---------------- Gate (parallel): one block per bj = b*2+s ----------------
// Threads 0..143 own one (cc,h) slot each: reduce tiles, write feats.
// Thread 0 runs the tiny softmax chain and broadcasts scale via LDS.
__global__ __launch_bounds__(192) void gate_kernel(
    const float* __restrict__ rs, const float* __restrict__ gn,
    const float* __restrict__ Wg1, const float* __restrict__ ag1p,
    const float* __restrict__ Wg2, const float* __restrict__ ag2p,
    float* __restrict__ out, float* __restrict__ m0buf,
    const int t, const int nt, const int li)
{
    const int bj  = blockIdx.x;          // 0..255
    const int tid = threadIdx.x;

    __shared__ float sums[144];          // [cc*9+h]
    __shared__ float sscale;

    if (tid < 144) {
        float s = 0.f;
        for (int tl = 0; tl < nt; ++tl)
            s += rs[(size_t)tl * RS_SLOT + (size_t)bj * 144 + tid];
        sums[tid] = s;
    }
    __syncthreads();

    if (tid == 0) {
        const float ag1 = ag1p[0], ag2 = ag2p[0];
        const float inv = 1.f / (9.f * (float)t);
        float pooled[CB];
#pragma unroll
        for (int cc = 0; cc < CB; ++cc) {
            float s = 0.f;
#pragma unroll
            for (int h = 0; h < HH; ++h) s += sums[cc * HH + h];
            pooled[cc] = s * inv;
        }
        float hm1[CB];
#pragma unroll
        for (int cc = 0; cc < CB; ++cc) {
            float s = 0.f;
#pragma unroll
            for (int c2 = 0; c2 < CB; ++c2) s = fmaf(Wg1[cc * CB + c2], pooled[c2], s);
            hm1[cc] = fprelu(s, ag1);
        }
        float h0 = 0.f, h1 = 0.f;
#pragma unroll
        for (int c2 = 0; c2 < CB; ++c2) {
            h0 = fmaf(Wg2[c2], hm1[c2], h0);
            h1 = fmaf(Wg2[CB + c2], hm1[c2], h1);
        }
        h0 = fprelu(h0, ag2); h1 = fprelu(h1, ag2);
        float mx = fmaxf(h0, h1);
        float e0 = __expf(h0 - mx), e1 = __expf(h1 - mx);
        float s0 = e0 / (e0 + e1), s1 = e1 / (e0 + e1);
        float a0 = s0 + gn[bj * 2 + 0], a1 = s1 + gn[bj * 2 + 1];   // TAU = 1
        float mx2 = fmaxf(a0, a1);
        float f0 = __expf(a0 - mx2), f1 = __expf(a1 - mx2);
        float m0 = f0 / (f0 + f1), m1 = f1 / (f0 + f1);
        sscale = m1 / (float)t;
        if ((bj & 1) == 0) m0buf[bj >> 1] = m0;   // next-level input scale
    }
    __syncthreads();

    if (tid < 144)
        out[(size_t)(bj * 144 + tid) * 9 + li] = sums[tid] * sscale;
}

extern "C" void kernel_launch(void* const* d_in, const int* in_sizes, int n_in,
                              void* d_out, int out_size, void* d_ws, size_t ws_size,
                              hipStream_t stream) {
    const float* x    = (const float*)d_in[0];
    const float* gn   = (const float*)d_in[1];
    const float* Wc1  = (const float*)d_in[2];
    const float* bc1  = (const float*)d_in[3];
    const float* bn1g = (const float*)d_in[4];
    const float* bn1b = (const float*)d_in[5];
    const float* ac1  = (const float*)d_in[6];
    const float* Wc2  = (const float*)d_in[7];
    const float* bc2  = (const float*)d_in[8];
    const float* bn2g = (const float*)d_in[9];
    const float* bn2b = (const float*)d_in[10];
    const float* ac2  = (const float*)d_in[11];
    const float* WP1  = (const float*)d_in[12];
    const float* aP   = (const float*)d_in[13];
    const float* WP2  = (const float*)d_in[14];
    const float* WU1  = (const float*)d_in[15];
    const float* aU   = (const float*)d_in[16];
    const float* WU2  = (const float*)d_in[17];
    const float* Wg1  = (const float*)d_in[18];
    const float* ag1  = (const float*)d_in[19];
    const float* Wg2  = (const float*)d_in[20];
    const float* ag2  = (const float*)d_in[21];
    float* out = (float*)d_out;

    char* ws = (char*)d_ws;
    const size_t sz0 = (size_t)128 * 9 * 2048 * 16 * 4;   // 150,994,944
    const size_t sz1 = sz0 / 2;                            //  75,497,472
    float* buf0 = (float*)ws;
    float* buf1 = (float*)(ws + sz0);
    float* rs   = (float*)(ws + sz0 + sz1);
    float* m0b  = (float*)(ws + sz0 + sz1 + (size_t)4 * RS_SLOT * 4);

    dim3 fgrid(9, 9, 128);
    front_kernel<<<fgrid, 256, 0, stream>>>(x, Wc1, bc1, bn1g, bn1b, ac1,
                                            Wc2, bc2, bn2g, bn2b, ac2, buf0);

    float* cur = buf0;
    float* nxt = buf1;
    int t = 1024;
    for (int i = 0; i < 9; ++i) {
        const int nt = (t + 255) >> 8;
        const float* m0p = (i == 0) ? nullptr : m0b;
        dim3 lgrid(128 * 9, nt);
        c_kernel<<<lgrid, 256, 0, stream>>>(cur, nxt, rs, m0p,
                                            WU1 + i * 768, aU + i, WU2 + i * 256, t);
        d_kernel<<<lgrid, 256, 0, stream>>>(cur, nxt, rs, m0p,
                                            WP1 + i * 768, aP + i, WP2 + i * 256, t);
        gate_kernel<<<256, 192, 0, stream>>>(
            rs, gn + i * 512, Wg1 + i * 256, ag1 + i, Wg2 + i * 32, ag2 + i,
            out, m0b, t, nt, i);
        float* tmp = cur; cur = nxt; nxt = tmp;
        t >>= 1;
    }
}